// Round 4
// baseline (66.700 us; speedup 1.0000x reference)
//
#include <hip/hip_runtime.h>
#include <math.h>

// Match the numpy/JAX reference op-for-op: no FMA contraction anywhere in
// the expressions that feed discrete decisions (alpha values, voxel trunc).
#pragma clang fp contract(off)

#define SPLIT 20
static constexpr int HH = 200, WW = 200, NPL = 256; // planes k = 0..256

__device__ __forceinline__ float alpha_of(float k, float sp, float src, float sdd) {
    return (k * sp - src) / sdd;   // reference: (k*spacing - src)/sdd, mul-sub-div
}

// Shared per-(ray,segment) tracer. All float expressions are verbatim from the
// round-3 passing kernel (bit-identical decision paths).
__device__ __forceinline__ void trace_seg(
    const float* __restrict__ vol, float* __restrict__ out,
    int it, int is, int seg,
    const float u[3], const float v[3], const float source[3],
    const float trans[3], const float src[3], const float spn[3])
{
    const float tc = (float)(it - HH/2 + 1) * 2.0f;   // DELX
    const float sc = (float)(is - WW/2 + 1) * 2.0f;   // DELY

    float sdd[3];
    float nrm2 = 0.0f;
    for (int a = 0; a < 3; ++a) {
        float tg = tc * u[a] + sc * v[a];
        tg = tg - source[a];     // + center
        tg = tg + trans[a];
        float d = (tg - src[a]) + 1e-8f;   // sdd = tgt - src + EPS
        sdd[a] = d;
        nrm2 = nrm2 + d * d;
    }
    const bool unit = (spn[0] == 1.0f) & (spn[1] == 1.0f) & (spn[2] == 1.0f);

    float amin = -INFINITY, amax = INFINITY;
    for (int a = 0; a < 3; ++a) {
        float a0 = (0.0f - src[a]) / sdd[a];
        float a1 = (256.0f * spn[a] - src[a]) / sdd[a];
        amin = fmaxf(amin, fminf(a0, a1));
        amax = fminf(amax, fmaxf(a0, a1));
    }

    float acc = 0.0f;
    if (amax > amin) {
        // Segment window (blo, bhi]; identical boundary arithmetic in all segs
        // of a ray, so the windows partition (amin, amax] exactly.
        const float blo = (seg == 0) ? amin
                        : amin + (amax - amin) * ((float)seg / (float)SPLIT);
        const float bhi = (seg == SPLIT - 1) ? amax
                        : amin + (amax - amin) * ((float)(seg + 1) / (float)SPLIT);

        float kf[3], kst[3], nexta[3];
        float prev = -INFINITY;   // largest in-range alpha <= blo

        for (int a = 0; a < 3; ++a) {
            const float sd = sdd[a], sr = src[a], spv = spn[a];
            const bool pos = sd > 0.0f;
            kst[a] = pos ? 1.0f : -1.0f;
            const float kseed = (blo * sd + sr) / spv;   // analytic seed
            int kk;
            if (pos) {   // alpha increases with k; pointer = smallest k with alpha(k) > blo
                kk = (int)floorf(kseed) + 1;
                kk = kk < 0 ? 0 : (kk > NPL + 1 ? NPL + 1 : kk);
                while (kk > 0    && alpha_of((float)(kk-1), spv, sr, sd) >  blo) --kk;
                while (kk <= NPL && alpha_of((float)kk,     spv, sr, sd) <= blo) ++kk;
                if (kk - 1 >= 0) {
                    float ap = alpha_of((float)(kk-1), spv, sr, sd);
                    if (ap >= amin && ap > prev) prev = ap;
                }
                nexta[a] = (kk <= NPL) ? alpha_of((float)kk, spv, sr, sd) : INFINITY;
            } else {     // alpha increases as k decreases; pointer = largest k with alpha(k) > blo
                kk = (int)ceilf(kseed) - 1;
                kk = kk > NPL ? NPL : (kk < -1 ? -1 : kk);
                while (kk < NPL && alpha_of((float)(kk+1), spv, sr, sd) >  blo) ++kk;
                while (kk >= 0  && alpha_of((float)kk,     spv, sr, sd) <= blo) --kk;
                if (kk + 1 <= NPL) {
                    float ap = alpha_of((float)(kk+1), spv, sr, sd);
                    if (ap >= amin && ap > prev) prev = ap;
                }
                nexta[a] = (kk >= 0) ? alpha_of((float)kk, spv, sr, sd) : INFINITY;
            }
            kf[a] = (float)kk;
        }

        // 3-way merge over this segment's window (exact ties advance together:
        // zero-width intervals contribute exactly 0 in the reference)
        for (int guard = 0; guard < 1024; ++guard) {
            const float q = fminf(fminf(nexta[0], nexta[1]), nexta[2]);
            if (!(q <= bhi)) break;

            const float step = q - prev;
            const float amid = 0.5f * (prev + q);

            // pts = src + amid * sdd  (reference order: mul, then add — no FMA)
            const float p0 = src[0] + amid * sdd[0];
            const float p1 = src[1] + amid * sdd[1];
            const float p2 = src[2] + amid * sdd[2];
            // idx = trunc(pts / spacing), clip [0,255]. p/1.0 == p exactly.
            float f0, f1, f2;
            if (unit) { f0 = p0; f1 = p1; f2 = p2; }
            else      { f0 = p0 / spn[0]; f1 = p1 / spn[1]; f2 = p2 / spn[2]; }
            f0 = fminf(fmaxf(f0, 0.0f), 255.0f);
            f1 = fminf(fmaxf(f1, 0.0f), 255.0f);
            f2 = fminf(fmaxf(f2, 0.0f), 255.0f);
            const int i0 = (int)f0, i1 = (int)f1, i2 = (int)f2;

            // vol = volume[::-1] along axis 0; lshl_add form: 3 VALU ops
            const int addr = ((((255 - i0) << 8) + i1) << 8) + i2;
            acc = fmaf(step, vol[addr], acc);
            prev = q;

            #pragma unroll
            for (int a = 0; a < 3; ++a) {
                if (nexta[a] == q) {
                    const float nk = kf[a] + kst[a];
                    kf[a] = nk;
                    const float al = alpha_of(nk, spn[a], src[a], sdd[a]);
                    nexta[a] = (nk >= 0.0f && nk <= 256.0f) ? al : INFINITY;
                }
            }
        }
    }

    atomicAdd(&out[it * WW + is], acc * sqrtf(nrm2));
}

// Computes the wave-uniform geometry once; main threads read it from d_ws.
// Bit-identical to computing it per-thread (same device trig, same order).
__global__ void drr_setup(const float* __restrict__ spacing,
                          const float* __restrict__ sdrP,
                          const float* __restrict__ thetaP,
                          const float* __restrict__ phiP,
                          const float* __restrict__ gammaP,
                          const float* __restrict__ bxP,
                          const float* __restrict__ byP,
                          const float* __restrict__ bzP,
                          float* __restrict__ ws)
{
    if (threadIdx.x != 0 || blockIdx.x != 0) return;
    const float sdr = sdrP[0];
    const float th = thetaP[0], ph = phiP[0], ga = gammaP[0];
    const float ct = cosf(th), st = sinf(th);
    const float cp = cosf(ph), sp = sinf(ph);
    const float cg = cosf(ga), sg = sinf(ga);

    const float rot[3][3] = {
        { ct*cp, ct*sp*sg - st*cg, ct*sp*cg + st*sg },
        { st*cp, st*sp*sg + ct*cg, st*sp*cg - ct*sg },
        { -sp,   cp*sg,            cp*cg            }
    };
    const float trans[3] = { bxP[0], byP[0], bzP[0] };
    for (int a = 0; a < 3; ++a) {
        const float source = sdr * rot[a][0];
        ws[0  + a] = (sdr * rot[a][1]) / sdr;   // u
        ws[3  + a] = (sdr * rot[a][2]) / sdr;   // v
        ws[6  + a] = source;                    // source
        ws[9  + a] = trans[a];                  // trans
        ws[12 + a] = source + trans[a];         // src
        ws[15 + a] = spacing[a];                // spn
    }
}

__global__ __launch_bounds__(128)
void drr_main(const float* __restrict__ vol,
              const float* __restrict__ ws,
              float* __restrict__ out)
{
    const int tid = blockIdx.x * blockDim.x + threadIdx.x;  // grid is exact
    const int seg = tid / (HH * WW);          // segment in high bits
    const int rid = tid - seg * (HH * WW);    // lanes = consecutive rid
    const int it  = rid % HH;                 // it fastest across lanes -> coalesced i2
    const int is  = rid / HH;

    float u[3], v[3], source[3], trans[3], src[3], spn[3];
    #pragma unroll
    for (int a = 0; a < 3; ++a) {
        u[a]      = ws[0  + a];
        v[a]      = ws[3  + a];
        source[a] = ws[6  + a];
        trans[a]  = ws[9  + a];
        src[a]    = ws[12 + a];
        spn[a]    = ws[15 + a];
    }
    trace_seg(vol, out, it, is, seg, u, v, source, trans, src, spn);
}

// Fallback if d_ws is unusably small: compute geometry per-thread (round-3 path).
__global__ __launch_bounds__(128)
void drr_mono(const float* __restrict__ vol,
              const float* __restrict__ spacing,
              const float* __restrict__ sdrP,
              const float* __restrict__ thetaP,
              const float* __restrict__ phiP,
              const float* __restrict__ gammaP,
              const float* __restrict__ bxP,
              const float* __restrict__ byP,
              const float* __restrict__ bzP,
              float* __restrict__ out)
{
    const int tid = blockIdx.x * blockDim.x + threadIdx.x;
    const int seg = tid / (HH * WW);
    const int rid = tid - seg * (HH * WW);
    const int it  = rid % HH;
    const int is  = rid / HH;

    const float sdr = sdrP[0];
    const float th = thetaP[0], ph = phiP[0], ga = gammaP[0];
    const float ct = cosf(th), st = sinf(th);
    const float cp = cosf(ph), sp = sinf(ph);
    const float cg = cosf(ga), sg = sinf(ga);
    const float rot[3][3] = {
        { ct*cp, ct*sp*sg - st*cg, ct*sp*cg + st*sg },
        { st*cp, st*sp*sg + ct*cg, st*sp*cg - ct*sg },
        { -sp,   cp*sg,            cp*cg            }
    };
    float u[3], v[3], source[3], trans[3], src[3], spn[3];
    trans[0] = bxP[0]; trans[1] = byP[0]; trans[2] = bzP[0];
    for (int a = 0; a < 3; ++a) {
        source[a] = sdr * rot[a][0];
        u[a] = (sdr * rot[a][1]) / sdr;
        v[a] = (sdr * rot[a][2]) / sdr;
        src[a] = source[a] + trans[a];
        spn[a] = spacing[a];
    }
    trace_seg(vol, out, it, is, seg, u, v, source, trans, src, spn);
}

extern "C" void kernel_launch(void* const* d_in, const int* in_sizes, int n_in,
                              void* d_out, int out_size, void* d_ws, size_t ws_size,
                              hipStream_t stream)
{
    const float* vol     = (const float*)d_in[0];
    const float* spacing = (const float*)d_in[1];
    const float* sdr     = (const float*)d_in[2];
    const float* theta   = (const float*)d_in[3];
    const float* phi     = (const float*)d_in[4];
    const float* gamma   = (const float*)d_in[5];
    const float* bx      = (const float*)d_in[6];
    const float* by      = (const float*)d_in[7];
    const float* bz      = (const float*)d_in[8];
    float* out = (float*)d_out;

    // re-zero the output every replay (graph captures this memset node);
    // required because partial sums are atomically accumulated.
    hipMemsetAsync(out, 0, (size_t)out_size * sizeof(float), stream);

    const int threads = HH * WW * SPLIT;   // 800000 = 6250 * 128 exactly
    const int block   = 128;
    const int grid    = threads / block;

    if (ws_size >= 18 * sizeof(float)) {
        float* ws = (float*)d_ws;
        drr_setup<<<1, 1, 0, stream>>>(spacing, sdr, theta, phi, gamma, bx, by, bz, ws);
        drr_main<<<grid, block, 0, stream>>>(vol, ws, out);
    } else {
        drr_mono<<<grid, block, 0, stream>>>(vol, spacing, sdr, theta, phi, gamma,
                                             bx, by, bz, out);
    }
}